// Round 1
// baseline (238.382 us; speedup 1.0000x reference)
//
#include <hip/hip_runtime.h>
#include <hip/hip_bf16.h>
#include <stdint.h>

// LightNet attention fwd. B=2, T=2048, HID=1024, H=8, DK=DV=128, LR=128.
// Contract (R1-R4): inputs fp32, output fp32.
//
// o_t[v] = scale * sum_k (q_t[k]/E_t[k]) * sum_{s<=t} e_s[k] v_s[v],
// e=exp(k), E=cumsum(e). Chunked Tc=128: pass1 (MFMA) Esum + Ut=(e^T V)^T;
// pass2 exclusive chunk prefix; pass3 (MFMA) intra(causal)+inter + atomic
// row sum-of-squares; norm_gate2 elementwise; final GEMM fully async.
//
// R9->R10: projection rewritten as 256x256-tile 8-phase GEMM (proj256):
// 8 waves (2x4), BK=64, 128 KiB LDS double-buffer, XOR-swizzled LDS
// (pre-swizzled global source + swizzled ds_read -- involution), counted
// vmcnt(8/10) across raw s_barriers (never drained in main loop), setprio
// around MFMA clusters. QKV fused as N=3072 (Wq/Wk/Wv contiguous) + G1 as
// 13th col-block (grid 16x13). Old 128^2 proj_kernel removed; gemm_bt
// (128^2 core) kept for the small-grid gate/output GEMMs.

typedef short short8 __attribute__((ext_vector_type(8)));
typedef float f32x4 __attribute__((ext_vector_type(4)));

#define T_SEQ 2048
#define HIDN  1024
#define SCALE 0.08838834764831845f   // 128^-0.5
#define LDSP  136                    // padded LDS row stride (shorts)

// ---------------- bf16 bit helpers ----------------
__device__ __forceinline__ float blo(unsigned int u){
  union{unsigned int i; float f;} v; v.i = u << 16; return v.f;
}
__device__ __forceinline__ float bhi(unsigned int u){
  union{unsigned int i; float f;} v; v.i = u & 0xffff0000u; return v.f;
}
__device__ __forceinline__ float bu2f(unsigned short u){
  union{unsigned int i; float f;} v; v.i = ((unsigned int)u) << 16; return v.f;
}
__device__ __forceinline__ unsigned short f2bu(float f){
  union{float f; unsigned int i;} v; v.f = f;
  unsigned int x = v.i;
  x += 0x7fffu + ((x >> 16) & 1u);     // RNE
  return (unsigned short)(x >> 16);
}
__device__ __forceinline__ void up8(const unsigned short* p, float* f){
  uint4 v = *(const uint4*)p;
  f[0]=blo(v.x); f[1]=bhi(v.x); f[2]=blo(v.y); f[3]=bhi(v.y);
  f[4]=blo(v.z); f[5]=bhi(v.z); f[6]=blo(v.w); f[7]=bhi(v.w);
}
__device__ __forceinline__ void async16(const void* g, void* l){
  __builtin_amdgcn_global_load_lds(
      (const __attribute__((address_space(1))) unsigned int*)g,
      (__attribute__((address_space(3))) unsigned int*)l, 16, 0, 0);
}
// raw barrier that the compiler cannot move memory ops across; does NOT
// drain vmcnt (that is the whole point vs __syncthreads()).
__device__ __forceinline__ void hard_barrier(){
  __builtin_amdgcn_sched_barrier(0);
  asm volatile("" ::: "memory");
  __builtin_amdgcn_s_barrier();
  asm volatile("" ::: "memory");
  __builtin_amdgcn_sched_barrier(0);
}
#define VMWAIT(N) asm volatile("s_waitcnt vmcnt(" #N ")" ::: "memory")

// ---------------- fused input cast + SumSq zeroing ------------------------
__global__ __launch_bounds__(256) void convert_all(
    const float* __restrict__ X,  const float* __restrict__ Wq,
    const float* __restrict__ Wk, const float* __restrict__ Wv,
    const float* __restrict__ Wg1,const float* __restrict__ Wg2,
    const float* __restrict__ gnw,const float* __restrict__ Wo,
    unsigned short* __restrict__ base, float* __restrict__ SumSq)
{
  int q = blockIdx.x * 256 + threadIdx.x;
  const float* src; unsigned short* dst; int rel = q;
  if (rel < 1048576)            { src = X;   dst = base;            }
  else if ((rel -= 1048576) < 262144) { src = Wq;  dst = base + 4194304; }
  else if ((rel -=  262144) < 262144) { src = Wk;  dst = base + 5242880; }
  else if ((rel -=  262144) < 262144) { src = Wv;  dst = base + 6291456; }
  else if ((rel -=  262144) < 262144) { src = Wo;  dst = base + 7340032; }
  else if ((rel -=  262144) <  32768) { src = Wg1; dst = base + 8388608; }
  else if ((rel -=   32768) <  32768) { src = Wg2; dst = base + 8519680; }
  else if ((rel -=   32768) <    256) { src = gnw; dst = base + 8650752; }
  else { rel -= 256;                              // zero SumSq (4096 floats)
    ((float4*)SumSq)[rel] = make_float4(0.f,0.f,0.f,0.f); return; }
  float4 v = ((const float4*)src)[rel];
  ushort4 o; o.x=f2bu(v.x); o.y=f2bu(v.y); o.z=f2bu(v.z); o.w=f2bu(v.w);
  ((ushort4*)dst)[rel] = o;
}

// ================= 256x256-tile 8-phase projection GEMM ===================
// C[4096 x 3200] = X[4096x1024] @ [Wq;Wk;Wv | Wg1]^T, per-matrix activation.
// grid (16, 13): by<12 -> QKV (col0=by*256), by==12 -> G1 (N=128, masked).
// 512 threads = 8 waves (2M x 4N); per-wave output 128x64; acc[MQ][NQ][4][2].
// LDS: [buf2][mat2][half2][128*64 bf16] = 128 KiB, half-tile = 128 rows.
// Swizzle: 16B chunk at logical (row, colbyte) stored at colbyte ^ ((row&7)<<4)
// (involution; applied to the global SOURCE so gload_lds dest stays linear).
// Per K-tile u: 4 quadrant phases; staging slots p1:B1(u+1) p2:A0(u+2)
// p3:B0(u+2) p4:A1(u+2); waits end-p1 vmcnt(8), end-p4 vmcnt(10)
// (tails: u==14 end-p4 vmcnt(4); u==15 end-p1 vmcnt(0)).
__global__ __launch_bounds__(512, 2) void proj256(
    const unsigned short* __restrict__ X,
    const unsigned short* __restrict__ Wqkv,   // Wq,Wk,Wv contiguous [3072][1024]
    const unsigned short* __restrict__ Wg1,    // [128][1024]
    unsigned short* __restrict__ QEV,          // Qb; Eb=+4194304; Vb=+8388608
    unsigned short* __restrict__ G1b)          // [4096][128]
{
  __shared__ unsigned short smem[65536];       // 128 KiB
  const int tid  = threadIdx.x;
  const int lane = tid & 63;
  const int w    = tid >> 6;                   // wave 0..7
  const int wm   = w >> 2, wn = w & 3;         // 2 x 4
  const int q    = lane >> 4, l15 = lane & 15;
  const int brow = blockIdx.x * 256;
  const bool isG1 = (blockIdx.y == 12);
  const unsigned short* Bp = isG1 ? Wg1 : Wqkv;
  const int bcol = isG1 ? 0 : blockIdx.y * 256;

  f32x4 acc[2][2][4][2] = {};
  short8 bA[8], bB0[4], bB1[4];

  // ---- stage half-tile (mat,hf) of K-tile tt: 2 x gload_lds / thread ----
  auto STAGE = [&](int tt, int mat, int hf){
    const unsigned short* src = mat ? Bp + (size_t)(bcol + hf*128)*1024
                                    : X  + (size_t)(brow + hf*128)*1024;
    unsigned short* dst = smem + (((tt&1)*2 + mat)*2 + hf)*8192;
    const int k0 = tt*64;
#pragma unroll
    for (int r=0;r<2;r++){
      int cb = r*512 + w*64;                   // wave-uniform chunk base
      int c  = cb + lane;
      int rh = c >> 3;                         // row in half-tile
      int colS = ((c & 7)*8) ^ ((rh & 7) << 3);// pre-swizzled source col
      async16(src + (size_t)rh*1024 + k0 + colS, dst + cb*8);
    }
  };
  // ---- ds_read fragment loads (swizzled, 2-way max bank aliasing) ----
  auto LDA = [&](int MQ, int buf){
#pragma unroll
    for (int i=0;i<4;i++){
      int rh = wm*64 + i*16 + l15;
      const unsigned short* base = smem + ((buf*2 + 0)*2 + MQ)*8192 + rh*64;
#pragma unroll
      for (int kk=0;kk<2;kk++)
        bA[i*2+kk] = *(const short8*)(base + (((kk*32) + q*8) ^ ((rh&7)<<3)));
    }
  };
  auto LDB = [&](short8 (&bB)[4], int NQ, int buf){
#pragma unroll
    for (int j=0;j<2;j++){
      int rh = wn*32 + j*16 + l15;
      const unsigned short* base = smem + ((buf*2 + 1)*2 + NQ)*8192 + rh*64;
#pragma unroll
      for (int kk=0;kk<2;kk++)
        bB[j*2+kk] = *(const short8*)(base + (((kk*32) + q*8) ^ ((rh&7)<<3)));
    }
  };
  auto MMA = [&](f32x4 (&AC)[4][2], short8 (&BV)[4]){
    __builtin_amdgcn_s_setprio(1);
#pragma unroll
    for (int i=0;i<4;i++)
#pragma unroll
      for (int j=0;j<2;j++)
#pragma unroll
        for (int kk=0;kk<2;kk++)
          AC[i][j] = __builtin_amdgcn_mfma_f32_16x16x32_bf16(
              bA[i*2+kk], BV[j*2+kk], AC[i][j], 0, 0, 0);
    __builtin_amdgcn_s_setprio(0);
  };

  // ---- prologue: A0(0) B0(0) A1(0) B1(0) A0(1) B0(1) A1(1) ----
  STAGE(0,0,0); STAGE(0,1,0); STAGE(0,0,1); STAGE(0,1,1);
  STAGE(1,0,0); STAGE(1,1,0); STAGE(1,0,1);
  VMWAIT(6);                                   // tile 0 fully landed
  hard_barrier();

#pragma unroll 2
  for (int u=0; u<16; ++u){
    const int buf = u & 1;
    // ---- phase 1: quadrant (MQ0,NQ0) ----
    LDA(0, buf); LDB(bB0, 0, buf);
    if (u < 15) STAGE(u+1, 1, 1);              // B1(u+1)
    hard_barrier();
    MMA(acc[0][0], bB0);
    if (u < 15) { VMWAIT(8); } else { VMWAIT(0); } // B1(u) & older landed
    hard_barrier();
    // ---- phase 2: quadrant (MQ0,NQ1) ----
    LDB(bB1, 1, buf);
    if (u < 14) STAGE(u+2, 0, 0);              // A0(u+2)
    hard_barrier();
    MMA(acc[0][1], bB1);
    hard_barrier();
    // ---- phase 3: quadrant (MQ1,NQ0) ----
    LDA(1, buf);
    if (u < 14) STAGE(u+2, 1, 0);              // B0(u+2)
    hard_barrier();
    MMA(acc[1][0], bB0);
    hard_barrier();
    // ---- phase 4: quadrant (MQ1,NQ1) ----
    if (u < 14) STAGE(u+2, 0, 1);              // A1(u+2)
    hard_barrier();
    MMA(acc[1][1], bB1);
    if (u < 14) { VMWAIT(10); } else { VMWAIT(4); } // A0/B0(u+1) & older landed
    hard_barrier();
  }

  // ---- epilogue: per-quadrant LDS staging (act applied in fp32) ----
  unsigned short* sC = smem;                   // 128 x 132 shorts
#pragma unroll
  for (int MQ=0;MQ<2;MQ++)
#pragma unroll
    for (int NQ=0;NQ<2;NQ++){
      const int m = isG1 ? 3 : ((blockIdx.y*256 + NQ*128) >> 10); // 0:silu 1:exp 2/3:none
#pragma unroll
      for (int i=0;i<4;i++)
#pragma unroll
        for (int j=0;j<2;j++)
#pragma unroll
          for (int r=0;r<4;r++){
            float v = acc[MQ][NQ][i][j][r];
            if (m == 0) v = v / (1.f + __expf(-v));
            else if (m == 1) v = __expf(v);
            int rr = wm*64 + i*16 + q*4 + r;
            int cc = wn*32 + j*16 + l15;
            sC[rr*132 + cc] = f2bu(v);
          }
      __syncthreads();
      if (!(isG1 && NQ == 1)){
#pragma unroll
        for (int k=0;k<4;k++){
          int c = tid + k*512;                 // 2048 chunks of 8 shorts
          int row = c >> 4, col8 = (c & 15)*8;
          int gr = brow + MQ*128 + row;
          uint4 val = *(const uint4*)(sC + row*132 + col8);
          if (isG1)
            *(uint4*)(G1b + (size_t)gr*128 + col8) = val;
          else {
            int gcol = blockIdx.y*256 + NQ*128 + col8;
            *(uint4*)(QEV + (size_t)(gcol>>10)*4194304
                          + (size_t)gr*1024 + (gcol & 1023)) = val;
          }
        }
      }
      __syncthreads();
    }
}

// ---------------- MFMA GEMM core: C(128x128)=A@B^T, BK=64 (2x32) ---------
__device__ __forceinline__ void gemm_core(
    const unsigned short* __restrict__ A, const unsigned short* __restrict__ B,
    int K, int row0, int col0,
    unsigned short* sA, unsigned short* sB, f32x4 acc[4][4], int tid)
{
  const int lane = tid & 63;
  const int wm = (tid >> 6) & 1, wn = tid >> 7;
  const int wb = tid & 192;                // wave-uniform chunk base
  for (int k0 = 0; k0 < K; k0 += 64){
    __syncthreads();                       // prev iter's LDS reads done
#pragma unroll
    for (int h = 0; h < 2; ++h){
#pragma unroll
      for (int r = 0; r < 2; ++r){
        int idx  = r*256 + tid;            // 512 chunks of 16B per sub-tile
        int mrow = idx >> 2, kc = (idx & 3) * 8;
        async16(A + (size_t)(row0 + mrow)*K + k0 + h*32 + kc,
                sA + (size_t)(h*512 + r*256 + wb)*8);
        async16(B + (size_t)(col0 + mrow)*K + k0 + h*32 + kc,
                sB + (size_t)(h*512 + r*256 + wb)*8);
      }
    }
    __syncthreads();                       // drains vmcnt before barrier
#pragma unroll
    for (int h = 0; h < 2; ++h){
      short8 av[4], bv[4];
#pragma unroll
      for (int i=0;i<4;i++)
        av[i] = *(const short8*)(sA + h*4096 + (size_t)(wm*64 + i*16 + (lane&15))*32 + (lane>>4)*8);
#pragma unroll
      for (int j=0;j<4;j++)
        bv[j] = *(const short8*)(sB + h*4096 + (size_t)(wn*64 + j*16 + (lane&15))*32 + (lane>>4)*8);
#pragma unroll
      for (int i=0;i<4;i++)
#pragma unroll
        for (int j=0;j<4;j++)
          acc[i][j] = __builtin_amdgcn_mfma_f32_16x16x32_bf16(av[i], bv[j], acc[i][j], 0, 0, 0);
    }
  }
}

// bf16 epilogue via LDS. act: 0 none, 1 silu/swish, 2 exp.
__device__ __forceinline__ void epilogue_lds(
    f32x4 acc[4][4], int row0, int col0, int tid, int ldc, int act,
    unsigned short* __restrict__ Cb, unsigned short* sC)
{
  const int lane = tid & 63;
  const int wm = (tid >> 6) & 1, wn = tid >> 7;
#pragma unroll
  for (int p=0;p<4;p++){
    __syncthreads();
    if (wm == (p>>1)){
#pragma unroll
      for (int ii=0; ii<2; ii++){
        int i = (p&1)*2 + ii;
        int lr = i*16 + ((lane>>4)<<2) - (p&1)*32;   // local row in [0,32)
#pragma unroll
        for (int j=0;j<4;j++){
          int col = wn*64 + j*16 + (lane&15);
#pragma unroll
          for (int r=0;r<4;r++){
            float v = acc[i][j][r];
            if (act == 1) v = v / (1.f + __expf(-v));
            else if (act == 2) v = __expf(v);
            sC[(lr+r)*128 + col] = f2bu(v);
          }
        }
      }
    }
    __syncthreads();
#pragma unroll
    for (int c = tid; c < 512; c += 256){  // 32 rows x 256B
      int rr = c >> 4, off = (c & 15)*8;
      *(uint4*)&Cb[(size_t)(row0 + p*32 + rr)*ldc + col0 + off] =
          *(const uint4*)&sC[rr*128 + off];
    }
  }
}

// fp32 direct epilogue (64B full-line segments).
__device__ __forceinline__ void epilogue_f32(
    f32x4 acc[4][4], int row0, int col0, int tid, int ldc,
    float* __restrict__ Cf)
{
  const int lane = tid & 63;
  const int wm = (tid >> 6) & 1, wn = tid >> 7;
#pragma unroll
  for (int i=0;i<4;i++){
    int rbase = row0 + wm*64 + i*16 + ((lane>>4)<<2);
#pragma unroll
    for (int j=0;j<4;j++){
      int col = col0 + wn*64 + j*16 + (lane&15);
#pragma unroll
      for (int r=0;r<4;r++)
        Cf[(size_t)(rbase + r)*ldc + col] = acc[i][j][r];
    }
  }
}

// Generic A@B^T. Cb nonnull -> bf16 LDS epilogue (act); else fp32 direct.
__global__ __launch_bounds__(256, 4) void gemm_bt(
    const unsigned short* __restrict__ A, const unsigned short* __restrict__ B,
    int K, int ldc, int act, float* __restrict__ Cf,
    unsigned short* __restrict__ Cb)
{
  __shared__ unsigned short sA[128*64], sB[128*64];
  int tid = threadIdx.x;
  int row0 = blockIdx.x * 128, col0 = blockIdx.y * 128;
  f32x4 acc[4][4] = {};
  gemm_core(A, B, K, row0, col0, sA, sB, acc, tid);
  if (Cb) epilogue_lds(acc, row0, col0, tid, ldc, act, Cb, sA);
  else    epilogue_f32(acc, row0, col0, tid, ldc, Cf);
}

// ---------------- pass 1 (MFMA): Esum[k], Ut[v][k] = sum_s V[s][v] e[s][k]
__global__ __launch_bounds__(512, 2) void attn_pass1(
    const unsigned short* __restrict__ Eb, const unsigned short* __restrict__ Vb,
    unsigned short* __restrict__ U, float* __restrict__ Esum)
{
  __shared__ unsigned short Vt[128*LDSP], Et[128*LDSP];   // ~70 KB
  __shared__ float seg_part[4*128];
  int tid = threadIdx.x;
  const int lane = tid & 63, quad = lane >> 4;
  const int w = tid >> 6, wm = w & 3, wn = w >> 2;
  const int Rb = wm*32, Cb = wn*64;
  int bh = blockIdx.x >> 4, ch = blockIdx.x & 15;
  int b = bh >> 3, h = bh & 7;
  size_t rowbase = (size_t)(b*T_SEQ + ch*128)*HIDN + h*128;

#pragma unroll
  for (int i=0;i<4;i++){                   // transpose-stage V and e
    int u = tid + i*512; int t = u >> 4, kc = (u & 15)*8;
    unsigned short tmp[8];
    *(uint4*)tmp = *(const uint4*)&Vb[rowbase + (size_t)t*HIDN + kc];
#pragma unroll
    for (int j=0;j<8;j++) Vt[(kc+j)*LDSP + t] = tmp[j];
    *(uint4*)tmp = *(const uint4*)&Eb[rowbase + (size_t)t*HIDN + kc];
#pragma unroll
    for (int j=0;j<8;j++) Et[(kc+j)*LDSP + t] = tmp[j];
  }
  __syncthreads();

  { // Esum[k] = row sums of Et
    int seg = tid >> 7, k = tid & 127;
    float s = 0.f;
    for (int c = seg*32; c < seg*32+32; ++c) s += bu2f(Et[k*LDSP + c]);
    seg_part[seg*128 + k] = s;
  }
  __syncthreads();
  if (tid < 128)
    Esum[(size_t)blockIdx.x*128 + tid] =
        seg_part[tid] + seg_part[128+tid] + seg_part[256+tid] + seg_part[384+tid];

  // Ut = Vt @ Et^T (contraction over s)
  f32x4 acc[2][4] = {};
  short8 av[2], bv[4];
#pragma unroll
  for (int s0=0; s0<128; s0+=32){
#pragma unroll
    for (int i=0;i<2;i++)
      av[i] = *(const short8*)(Vt + (Rb + i*16 + (lane&15))*LDSP + s0 + quad*8);
#pragma unroll
    for (int j=0;j<4;j++)
      bv[j] = *(const short8*)(Et + (Cb + j*16 + (lane&15))*LDSP + s0 + quad*8);
#pragma unroll
    for (int i=0;i<2;i++)
#pragma unroll
      for (int j=0;j<4;j++)
        acc[i][j] = __builtin_amdgcn_mfma_f32_16x16x32_bf16(av[i], bv[j], acc[i][j], 0,0,0);
  }
  __syncthreads();                         // all Et/Vt reads done

  // stage C (bf16) into Et region, coalesced copy-out
#pragma unroll
  for (int i=0;i<2;i++)
#pragma unroll
    for (int j=0;j<4;j++){
      int k = Cb + j*16 + (lane&15);
#pragma unroll
      for (int r=0;r<4;r++){
        int v = Rb + i*16 + quad*4 + r;
        Et[v*LDSP + k] = f2bu(acc[i][j][r]);
      }
    }
  __syncthreads();
  unsigned short* Ub = U + (size_t)blockIdx.x*16384;
#pragma unroll
  for (int i=0;i<4;i++){
    int u = tid + i*512; int v = u >> 4, kc = (u & 15)*8;
    *(uint4*)&Ub[v*128 + kc] = *(const uint4*)&Et[v*LDSP + kc];
  }
}

// ---------------- pass 2: exclusive prefix over chunks (in place) ----------
__global__ __launch_bounds__(256) void attn_pass2(
    unsigned short* __restrict__ U, float* __restrict__ Esum)
{
  int bh = blockIdx.x >> 4, sl = blockIdx.x & 15;
  int p = sl*1024 + threadIdx.x*4;
  float r0=0.f, r1=0.f, r2=0.f, r3=0.f;
  for (int c=0;c<16;c++){
    ushort4* ptr = (ushort4*)&U[(size_t)(bh*16 + c)*16384 + p];
    ushort4 t = *ptr;
    ushort4 w;
    w.x=f2bu(r0); w.y=f2bu(r1); w.z=f2bu(r2); w.w=f2bu(r3);
    *ptr = w;
    r0 += bu2f(t.x); r1 += bu2f(t.y); r2 += bu2f(t.z); r3 += bu2f(t.w);
  }
  if (sl == 0 && threadIdx.x < 128){
    float r = 0.f;
    for (int c=0;c<16;c++){
      float* q = &Esum[(size_t)(bh*16 + c)*128 + threadIdx.x];
      float t = *q; *q = r; r += t;
    }
  }
}

// ---------------- pass 3 (MFMA): o = qn@Cprev + causal(qn@e^T)@V + SumSq --
// 2 LDS buffers (68 KB -> 2 blocks/CU). Ut read DIRECT from global (no
// reuse; L2-resident). bufA: Q->qn->P->Ostage ; bufB: e->Vt.
__global__ __launch_bounds__(512, 4) void attn_pass3(
    const unsigned short* __restrict__ Eb, const unsigned short* __restrict__ Qb,
    const unsigned short* __restrict__ Vb, const unsigned short* __restrict__ U,
    const float* __restrict__ Esum, unsigned short* __restrict__ Oatt,
    float* __restrict__ SumSq)
{
  __shared__ unsigned short smem[2*128*LDSP];     // 68 KB
  __shared__ float seg_part[4*128];
  unsigned short* bufA = smem;
  unsigned short* bufB = smem + 128*LDSP;

  int tid = threadIdx.x;
  const int lane = tid & 63, quad = lane >> 4;
  const int w = tid >> 6, wm = w & 3, wn = w >> 2;
  const int Rb = wm*32, Cb = wn*64;
  int bh = blockIdx.x >> 4, ch = blockIdx.x & 15;
  int b = bh >> 3, h = bh & 7;
  size_t rowbase = (size_t)(b*T_SEQ + ch*128)*HIDN + h*128;
  const unsigned short* Ublk = U + (size_t)blockIdx.x*16384;

  // ---- stage Q, e ----
#pragma unroll
  for (int i=0;i<4;i++){
    int u = tid + i*512; int t = u >> 4, kc = (u & 15)*8;
    *(uint4*)&bufA[t*LDSP + kc] = *(const uint4*)&Qb[rowbase + (size_t)t*HIDN + kc];
    *(uint4*)&bufB[t*LDSP + kc] = *(const uint4*)&Eb[rowbase + (size_t)t*HIDN + kc];
  }
  __syncthreads();

  // ---- qn = q*SCALE/E_t ; 4-way segmented inclusive cumsum over t ----
  {
    int col = tid & 127, seg = tid >> 7;
    float psum = 0.f;
    for (int s = seg*32; s < seg*32+32; ++s) psum += bu2f(bufB[s*LDSP + col]);
    seg_part[seg*128 + col] = psum;
    __syncthreads();
    float run = Esum[(size_t)blockIdx.x*128 + col];
    for (int ss=0; ss<4; ++ss) if (ss < seg) run += seg_part[ss*128 + col];
    for (int s = seg*32; s < seg*32+32; ++s){
      run += bu2f(bufB[s*LDSP + col]);
      float q = bu2f(bufA[s*LDSP + col]);
      bufA[s*LDSP + col] = f2bu(q * SCALE * __builtin_amdgcn_rcpf(run));
    }
  }
  __syncthreads();

  // ---- inter: O = QN @ Ut^T (Ut direct from global) ; scores: P = QN@E^T --
  f32x4 accO[2][4] = {}, accP[2][4] = {};
  short8 av[2], bv[4];
#pragma unroll
  for (int k0=0; k0<128; k0+=32){
#pragma unroll
    for (int i=0;i<2;i++)
      av[i] = *(const short8*)(bufA + (Rb + i*16 + (lane&15))*LDSP + k0 + quad*8);
#pragma unroll
    for (int j=0;j<4;j++)
      bv[j] = *(const short8*)(Ublk + (size_t)(Cb + j*16 + (lane&15))*128 + k0 + quad*8);
#pragma unroll
    for (int i=0;i<2;i++)
#pragma unroll
      for (int j=0;j<4;j++)
        accO[i][j] = __builtin_amdgcn_mfma_f32_16x16x32_bf16(av[i], bv[j], accO[i][j], 0,0,0);
#pragma unroll
    for (int j=0;j<4;j++)
      bv[j] = *(const short8*)(bufB + (Cb + j*16 + (lane&15))*LDSP + k0 + quad*8);
#pragma unroll
    for (int i=0;i<2;i++)
#pragma unroll
      for (int j=0;j<4;j++)
        accP[i][j] = __builtin_amdgcn_mfma_f32_16x16x32_bf16(av[i], bv[j], accP[i][j], 0,0,0);
  }
  __syncthreads();

  // ---- masked P -> bufA [t][s] ; V^T -> bufB [v][s] ----
#pragma unroll
  for (int i=0;i<2;i++){
#pragma unroll
    for (int j=0;j<4;j++){
      int s = Cb + j*16 + (lane&15);
#pragma unroll
      for (int r=0;r<4;r++){
        int t = Rb + i*16 + quad*4 + r;
        bufA[t*LDSP + s] = f2bu(s <= t ? accP[i][j][r] : 0.f);
      }
    }
  }
#pragma unroll
  for (int i=0;i<4;i++){
    int u = tid + i*512; int t = u >> 4, kc = (u & 15)*8;
    unsigned short tmp[8];
    *(uint4*)tmp = *(const uint4*)&Vb[rowbase + (size_t)t*HIDN + kc];
#pragma unroll
    for (int j=0;j<8;j++) bufB[(kc+j)*LDSP + t] = tmp[j];
  }
  __syncthreads();

  // ---- intra: O += P @ Vt^T ----
#pragma unroll
  for (int k0=0; k0<128; k0+=32){
#pragma unroll
    for (int i=0;i<2;i++)
      av[i] = *(const short8*)(bufA + (Rb + i*16 + (lane&15))*LDSP + k0 + quad*8);
#pragma unroll
    for (int j=0;j<4;j++)
      bv[j] = *(const short8*)(bufB + (Cb + j*16 + (lane&15))*LDSP + k0 + quad*8);
#pragma unroll
    for (int i=0;i<2;i++)
#pragma unroll
      for (int j=0;j<4;j++)
        accO[i][j] = __builtin_amdgcn_mfma_f32_16x16x32_bf16(av[i], bv[j], accO[i][j], 0,0,0);
  }
  __syncthreads();                        // all bufA (P) reads done

  // ---- O -> bufA (bf16) ----
#pragma unroll
  for (int i=0;i<2;i++){
#pragma unroll
    for (int j=0;j<4;j++){
      int v = Cb + j*16 + (lane&15);
#pragma unroll
      for (int r=0;r<4;r++){
        int t = Rb + i*16 + quad*4 + r;
        bufA[t*LDSP + v] = f2bu(accO[i][j][r]);
      }
    }
  }
  __syncthreads();

  // ---- per-row sum of squares (this head's 128 cols) ----
  {
    int seg = tid >> 7, row = tid & 127;
    float s = 0.f;
    for (int c = seg*32; c < seg*32+32; ++c){
      float x = bu2f(bufA[row*LDSP + c]); s += x*x;
    }
    seg_part[seg*128 + row] = s;
  }
  // ---- coalesced O write ----
#pragma unroll
  for (int i=0;i<4;i++){
    int u = tid + i*512; int t = u >> 4, kc = (u & 15)*8;
    *(uint4*)&Oatt[rowbase + (size_t)t*HIDN + kc] = *(const uint4*)&bufA[t*LDSP + kc];
  }
  __syncthreads();
  if (tid < 128){
    float s = seg_part[tid] + seg_part[128+tid] + seg_part[256+tid] + seg_part[384+tid];
    atomicAdd(&SumSq[(size_t)b*T_SEQ + ch*128 + tid], s);
  }
}

// ---- norm_gate2: elementwise RMSNorm(SumSq)*gnw*swish-gate -> bf16 -------
__global__ __launch_bounds__(256) void norm_gate2(
    const unsigned short* __restrict__ Oatt, const unsigned short* __restrict__ Gt,
    const unsigned short* __restrict__ gnw, const float* __restrict__ SumSq,
    unsigned short* __restrict__ Onorm)
{
  int row = blockIdx.x, tid = threadIdx.x;
  float rstd = rsqrtf(SumSq[row] * (1.f/1024.f) + 1e-5f);
  ushort4 o4 = *(const ushort4*)&Oatt[(size_t)row*HIDN + tid*4];
  ushort4 g4 = *(const ushort4*)&Gt  [(size_t)row*HIDN + tid*4];
  ushort4 w4 = *(const ushort4*)&gnw[tid*4];
  ushort4 r4;
  r4.x = f2bu(bu2f(o4.x) * rstd * bu2f(w4.x) * bu2f(g4.x));
  r4.y = f2bu(bu2f(o4.y) * rstd * bu2f(w4.y) * bu2f(g4.y));
  r4.z = f2bu(bu2f(o4.z) * rstd * bu2f(w4.z) * bu2f(g4.z));
  r4.w = f2bu(bu2f(o4.w) * rstd * bu2f(w4.w) * bu2f(g4.w));
  *(ushort4*)&Onorm[(size_t)row*HIDN + tid*4] = r4;
}

// ---------------- launch ----------------
extern "C" void kernel_launch(void* const* d_in, const int* in_sizes, int n_in,
                              void* d_out, int out_size, void* d_ws, size_t ws_size,
                              hipStream_t stream) {
  unsigned short* wsS = (unsigned short*)d_ws;     // ~69 MiB used

  unsigned short* Xc   = wsS;              // 4,194,304
  unsigned short* Wqc  = wsS + 4194304;    // Wq,Wk,Wv contiguous = [3072][1024]
  unsigned short* Wg1c = wsS + 8388608;
  unsigned short* Wg2c = wsS + 8519680;
  unsigned short* gnwc = wsS + 8650752;
  unsigned short* Woc  = wsS + 7340032;
  unsigned short* Qb   = wsS + 8651776;    // Qb,Eb,Vb contiguous (stride 4194304)
  unsigned short* Eb   = wsS + 12846080;   // e = exp(k), bf16
  unsigned short* Vb   = wsS + 17040384;
  unsigned short* G1b  = wsS + 21234688;
  unsigned short* Gt   = wsS + 21758976;
  unsigned short* Ub   = wsS + 25953280;
  unsigned short* Oattb= wsS + 30147584;
  float*          Esum = (float*)(wsS + 34341888);  // 32,768 floats
  float*          SumSq= (float*)(wsS + 34407424);  //  4,096 floats
  unsigned short* Onorm = Qb;              // Q dead after pass3

  convert_all<<<8453, 256, 0, stream>>>(
      (const float*)d_in[0], (const float*)d_in[1], (const float*)d_in[2],
      (const float*)d_in[3], (const float*)d_in[4], (const float*)d_in[5],
      (const float*)d_in[6], (const float*)d_in[7], wsS, SumSq);

  proj256   <<<dim3(16,13), 512, 0, stream>>>(Xc, Wqc, Wg1c, Qb, G1b);
  gemm_bt   <<<dim3(32,8),  256, 0, stream>>>(G1b, Wg2c, 128, HIDN, 1, nullptr, Gt);
  attn_pass1<<<256, 512, 0, stream>>>(Eb, Vb, Ub, Esum);
  attn_pass2<<<256, 256, 0, stream>>>(Ub, Esum);
  attn_pass3<<<256, 512, 0, stream>>>(Eb, Qb, Vb, Ub, Esum, Oattb, SumSq);
  norm_gate2<<<4096, 256, 0, stream>>>(Oattb, Gt, gnwc, SumSq, Onorm);
  gemm_bt   <<<dim3(32,8),  256, 0, stream>>>(Onorm, Woc, HIDN, HIDN, 0,
                                              (float*)d_out, nullptr);
}

// Round 2
// 196.052 us; speedup vs baseline: 1.2159x; 1.2159x over previous
//
#include <hip/hip_runtime.h>
#include <hip/hip_bf16.h>
#include <stdint.h>

// LightNet attention fwd. B=2, T=2048, HID=1024, H=8, DK=DV=128, LR=128.
// Contract (R1-R4): inputs fp32, output fp32.
//
// o_t[v] = scale * sum_k (q_t[k]/E_t[k]) * sum_{s<=t} e_s[k] v_s[v],
// e=exp(k), E=cumsum(e). Chunked Tc=128: pass1 (MFMA) Esum + Ut=(e^T V)^T;
// pass2 exclusive chunk prefix; pass3 (MFMA) intra(causal)+inter + atomic
// row sum-of-squares; norm_gate2 elementwise; final GEMM fully async.
//
// R10->R11: 8-phase proj256 reverted (prediction mismatch: 79.9us vs 44.5us
// baseline; barrier-lockstep at 1 block/CU exposed all latency). Kept the
// verified swizzle knowledge (R1: conflicts -> exactly 0 under XOR involution
// => LDS serves wave64 vector ops in 8-lane subgroups):
//  - gemm_core: unified [128][64] LDS tile, chunk-XOR (row&7) swizzle via
//    pre-swizzled global source + swizzled frag reads. 4-way -> conflict-free.
//  - pass1/pass3 transpose-stores: t-column rotation by (v&120) kills the
//    32-way same-bank store conflict (was 2.39M cycles in pass3); readers
//    (MFMA frags, Esum sums) apply the same rotation. Bit-exact layout-only.

typedef short short8 __attribute__((ext_vector_type(8)));
typedef float f32x4 __attribute__((ext_vector_type(4)));

#define T_SEQ 2048
#define HIDN  1024
#define SCALE 0.08838834764831845f   // 128^-0.5
#define LDSP  136                    // padded LDS row stride (shorts)

// ---------------- bf16 bit helpers ----------------
__device__ __forceinline__ float blo(unsigned int u){
  union{unsigned int i; float f;} v; v.i = u << 16; return v.f;
}
__device__ __forceinline__ float bhi(unsigned int u){
  union{unsigned int i; float f;} v; v.i = u & 0xffff0000u; return v.f;
}
__device__ __forceinline__ float bu2f(unsigned short u){
  union{unsigned int i; float f;} v; v.i = ((unsigned int)u) << 16; return v.f;
}
__device__ __forceinline__ unsigned short f2bu(float f){
  union{float f; unsigned int i;} v; v.f = f;
  unsigned int x = v.i;
  x += 0x7fffu + ((x >> 16) & 1u);     // RNE
  return (unsigned short)(x >> 16);
}
__device__ __forceinline__ void async16(const void* g, void* l){
  __builtin_amdgcn_global_load_lds(
      (const __attribute__((address_space(1))) unsigned int*)g,
      (__attribute__((address_space(3))) unsigned int*)l, 16, 0, 0);
}

// ---------------- fused input cast + SumSq zeroing ------------------------
__global__ __launch_bounds__(256) void convert_all(
    const float* __restrict__ X,  const float* __restrict__ Wq,
    const float* __restrict__ Wk, const float* __restrict__ Wv,
    const float* __restrict__ Wg1,const float* __restrict__ Wg2,
    const float* __restrict__ gnw,const float* __restrict__ Wo,
    unsigned short* __restrict__ base, float* __restrict__ SumSq)
{
  int q = blockIdx.x * 256 + threadIdx.x;
  const float* src; unsigned short* dst; int rel = q;
  if (rel < 1048576)            { src = X;   dst = base;            }
  else if ((rel -= 1048576) < 262144) { src = Wq;  dst = base + 4194304; }
  else if ((rel -=  262144) < 262144) { src = Wk;  dst = base + 5242880; }
  else if ((rel -=  262144) < 262144) { src = Wv;  dst = base + 6291456; }
  else if ((rel -=  262144) < 262144) { src = Wo;  dst = base + 7340032; }
  else if ((rel -=  262144) <  32768) { src = Wg1; dst = base + 8388608; }
  else if ((rel -=   32768) <  32768) { src = Wg2; dst = base + 8519680; }
  else if ((rel -=   32768) <    256) { src = gnw; dst = base + 8650752; }
  else { rel -= 256;                              // zero SumSq (4096 floats)
    ((float4*)SumSq)[rel] = make_float4(0.f,0.f,0.f,0.f); return; }
  float4 v = ((const float4*)src)[rel];
  ushort4 o; o.x=f2bu(v.x); o.y=f2bu(v.y); o.z=f2bu(v.z); o.w=f2bu(v.w);
  ((ushort4*)dst)[rel] = o;
}

// ---------------- MFMA GEMM core: C(128x128)=A@B^T, BK=64 ----------------
// LDS tile [128 rows][8 chunks of 16B]; chunk cl of row r holds source
// chunk cl^(r&7) (involution; applied on the global source address so the
// global_load_lds destination stays linear). Frag reads use the same XOR:
// lanes 0-7 hit 8 distinct quad-bank groups -> conflict-free.
__device__ __forceinline__ void gemm_core(
    const unsigned short* __restrict__ A, const unsigned short* __restrict__ B,
    int K, int row0, int col0,
    unsigned short* sA, unsigned short* sB, f32x4 acc[4][4], int tid)
{
  const int lane = tid & 63;
  const int wm = (tid >> 6) & 1, wn = tid >> 7;
  const int wb = tid & 192;                // wave-uniform chunk base
  for (int k0 = 0; k0 < K; k0 += 64){
    __syncthreads();                       // prev iter's LDS reads done
#pragma unroll
    for (int r = 0; r < 4; ++r){
      int idx  = r*256 + tid;              // 1024 chunks of 16B per tile
      int mrow = idx >> 3;                 // row 0..127
      int kc   = ((idx & 7) ^ (mrow & 7)) * 8;   // pre-swizzled source col
      async16(A + (size_t)(row0 + mrow)*K + k0 + kc,
              sA + (size_t)(r*256 + wb)*8);
      async16(B + (size_t)(col0 + mrow)*K + k0 + kc,
              sB + (size_t)(r*256 + wb)*8);
    }
    __syncthreads();                       // drains vmcnt before barrier
#pragma unroll
    for (int h = 0; h < 2; ++h){
      short8 av[4], bv[4];
#pragma unroll
      for (int i=0;i<4;i++){
        int ra = wm*64 + i*16 + (lane&15);
        av[i] = *(const short8*)(sA + (size_t)ra*64
                                 + (((h*4 + (lane>>4)) ^ (ra & 7)) * 8));
      }
#pragma unroll
      for (int j=0;j<4;j++){
        int rb = wn*64 + j*16 + (lane&15);
        bv[j] = *(const short8*)(sB + (size_t)rb*64
                                 + (((h*4 + (lane>>4)) ^ (rb & 7)) * 8));
      }
#pragma unroll
      for (int i=0;i<4;i++)
#pragma unroll
        for (int j=0;j<4;j++)
          acc[i][j] = __builtin_amdgcn_mfma_f32_16x16x32_bf16(av[i], bv[j], acc[i][j], 0, 0, 0);
    }
  }
}

// bf16 epilogue via LDS. act: 0 none, 1 silu/swish, 2 exp.
__device__ __forceinline__ void epilogue_lds(
    f32x4 acc[4][4], int row0, int col0, int tid, int ldc, int act,
    unsigned short* __restrict__ Cb, unsigned short* sC)
{
  const int lane = tid & 63;
  const int wm = (tid >> 6) & 1, wn = tid >> 7;
#pragma unroll
  for (int p=0;p<4;p++){
    __syncthreads();
    if (wm == (p>>1)){
#pragma unroll
      for (int ii=0; ii<2; ii++){
        int i = (p&1)*2 + ii;
        int lr = i*16 + ((lane>>4)<<2) - (p&1)*32;   // local row in [0,32)
#pragma unroll
        for (int j=0;j<4;j++){
          int col = wn*64 + j*16 + (lane&15);
#pragma unroll
          for (int r=0;r<4;r++){
            float v = acc[i][j][r];
            if (act == 1) v = v / (1.f + __expf(-v));
            else if (act == 2) v = __expf(v);
            sC[(lr+r)*128 + col] = f2bu(v);
          }
        }
      }
    }
    __syncthreads();
#pragma unroll
    for (int c = tid; c < 512; c += 256){  // 32 rows x 256B
      int rr = c >> 4, off = (c & 15)*8;
      *(uint4*)&Cb[(size_t)(row0 + p*32 + rr)*ldc + col0 + off] =
          *(const uint4*)&sC[rr*128 + off];
    }
  }
}

// fp32 direct epilogue (64B full-line segments).
__device__ __forceinline__ void epilogue_f32(
    f32x4 acc[4][4], int row0, int col0, int tid, int ldc,
    float* __restrict__ Cf)
{
  const int lane = tid & 63;
  const int wm = (tid >> 6) & 1, wn = tid >> 7;
#pragma unroll
  for (int i=0;i<4;i++){
    int rbase = row0 + wm*64 + i*16 + ((lane>>4)<<2);
#pragma unroll
    for (int j=0;j<4;j++){
      int col = col0 + wn*64 + j*16 + (lane&15);
#pragma unroll
      for (int r=0;r<4;r++)
        Cf[(size_t)(rbase + r)*ldc + col] = acc[i][j][r];
    }
  }
}

// Fused QKV+G1 projection. grid (32, 25): y<8 Q(silu), <16 K->e (exp),
// <24 V, ==24 G1.
__global__ __launch_bounds__(256, 4) void proj_kernel(
    const unsigned short* __restrict__ X,
    const unsigned short* __restrict__ Wq, const unsigned short* __restrict__ Wk,
    const unsigned short* __restrict__ Wv, const unsigned short* __restrict__ Wg1,
    unsigned short* __restrict__ Qb, unsigned short* __restrict__ Eb,
    unsigned short* __restrict__ Vb, unsigned short* __restrict__ G1b)
{
  __shared__ unsigned short sA[128*64], sB[128*64];
  int tid = threadIdx.x;
  int which = blockIdx.y >> 3;
  const unsigned short* Bp = (which==0)?Wq:(which==1)?Wk:(which==2)?Wv:Wg1;
  int row0 = blockIdx.x * 128;
  int col0 = (which==3) ? 0 : (blockIdx.y & 7) * 128;
  f32x4 acc[4][4] = {};
  gemm_core(X, Bp, HIDN, row0, col0, sA, sB, acc, tid);
  if      (which==0) epilogue_lds(acc,row0,col0,tid,HIDN,1,Qb, sA);
  else if (which==1) epilogue_lds(acc,row0,col0,tid,HIDN,2,Eb, sA);  // e=exp(k)
  else if (which==2) epilogue_lds(acc,row0,col0,tid,HIDN,0,Vb, sA);
  else               epilogue_lds(acc,row0,col0,tid,128 ,0,G1b,sA);
}

// Generic A@B^T. Cb nonnull -> bf16 LDS epilogue (act); else fp32 direct.
__global__ __launch_bounds__(256, 4) void gemm_bt(
    const unsigned short* __restrict__ A, const unsigned short* __restrict__ B,
    int K, int ldc, int act, float* __restrict__ Cf,
    unsigned short* __restrict__ Cb)
{
  __shared__ unsigned short sA[128*64], sB[128*64];
  int tid = threadIdx.x;
  int row0 = blockIdx.x * 128, col0 = blockIdx.y * 128;
  f32x4 acc[4][4] = {};
  gemm_core(A, B, K, row0, col0, sA, sB, acc, tid);
  if (Cb) epilogue_lds(acc, row0, col0, tid, ldc, act, Cb, sA);
  else    epilogue_f32(acc, row0, col0, tid, ldc, Cf);
}

// ---------------- pass 1 (MFMA): Esum[k], Ut[v][k] = sum_s V[s][v] e[s][k]
// Transpose-stores rotate the t-column by (v&120): kills the 32-way
// same-bank store conflict; all readers apply the same rotation.
__global__ __launch_bounds__(512, 2) void attn_pass1(
    const unsigned short* __restrict__ Eb, const unsigned short* __restrict__ Vb,
    unsigned short* __restrict__ U, float* __restrict__ Esum)
{
  __shared__ unsigned short Vt[128*LDSP], Et[128*LDSP];   // ~70 KB
  __shared__ float seg_part[4*128];
  int tid = threadIdx.x;
  const int lane = tid & 63, quad = lane >> 4;
  const int w = tid >> 6, wm = w & 3, wn = w >> 2;
  const int Rb = wm*32, Cb = wn*64;
  int bh = blockIdx.x >> 4, ch = blockIdx.x & 15;
  int b = bh >> 3, h = bh & 7;
  size_t rowbase = (size_t)(b*T_SEQ + ch*128)*HIDN + h*128;

#pragma unroll
  for (int i=0;i<4;i++){                   // transpose-stage V and e (rotated)
    int u = tid + i*512; int t = u >> 4, kc = (u & 15)*8;
    int trot = (t + kc) & 127;             // rotation: v&120 == kc for v=kc+j
    unsigned short tmp[8];
    *(uint4*)tmp = *(const uint4*)&Vb[rowbase + (size_t)t*HIDN + kc];
#pragma unroll
    for (int j=0;j<8;j++) Vt[(kc+j)*LDSP + trot] = tmp[j];
    *(uint4*)tmp = *(const uint4*)&Eb[rowbase + (size_t)t*HIDN + kc];
#pragma unroll
    for (int j=0;j<8;j++) Et[(kc+j)*LDSP + trot] = tmp[j];
  }
  __syncthreads();

  { // Esum[k] = row sums of Et (rotated reads)
    int seg = tid >> 7, k = tid & 127;
    float s = 0.f;
    for (int c = seg*32; c < seg*32+32; ++c)
      s += bu2f(Et[k*LDSP + ((c + (k & 120)) & 127)]);
    seg_part[seg*128 + k] = s;
  }
  __syncthreads();
  if (tid < 128)
    Esum[(size_t)blockIdx.x*128 + tid] =
        seg_part[tid] + seg_part[128+tid] + seg_part[256+tid] + seg_part[384+tid];

  // Ut = Vt @ Et^T (contraction over s)
  f32x4 acc[2][4] = {};
  short8 av[2], bv[4];
#pragma unroll
  for (int s0=0; s0<128; s0+=32){
#pragma unroll
    for (int i=0;i<2;i++){
      int ra = Rb + i*16 + (lane&15);
      av[i] = *(const short8*)(Vt + ra*LDSP + ((s0 + quad*8 + (ra & 120)) & 127));
    }
#pragma unroll
    for (int j=0;j<4;j++){
      int rb = Cb + j*16 + (lane&15);
      bv[j] = *(const short8*)(Et + rb*LDSP + ((s0 + quad*8 + (rb & 120)) & 127));
    }
#pragma unroll
    for (int i=0;i<2;i++)
#pragma unroll
      for (int j=0;j<4;j++)
        acc[i][j] = __builtin_amdgcn_mfma_f32_16x16x32_bf16(av[i], bv[j], acc[i][j], 0,0,0);
  }
  __syncthreads();                         // all Et/Vt reads done

  // stage C (bf16) into Et region, coalesced copy-out (row-major, no rot)
#pragma unroll
  for (int i=0;i<2;i++)
#pragma unroll
    for (int j=0;j<4;j++){
      int k = Cb + j*16 + (lane&15);
#pragma unroll
      for (int r=0;r<4;r++){
        int v = Rb + i*16 + quad*4 + r;
        Et[v*LDSP + k] = f2bu(acc[i][j][r]);
      }
    }
  __syncthreads();
  unsigned short* Ub = U + (size_t)blockIdx.x*16384;
#pragma unroll
  for (int i=0;i<4;i++){
    int u = tid + i*512; int v = u >> 4, kc = (u & 15)*8;
    *(uint4*)&Ub[v*128 + kc] = *(const uint4*)&Et[v*LDSP + kc];
  }
}

// ---------------- pass 2: exclusive prefix over chunks (in place) ----------
__global__ __launch_bounds__(256) void attn_pass2(
    unsigned short* __restrict__ U, float* __restrict__ Esum)
{
  int bh = blockIdx.x >> 4, sl = blockIdx.x & 15;
  int p = sl*1024 + threadIdx.x*4;
  float r0=0.f, r1=0.f, r2=0.f, r3=0.f;
  for (int c=0;c<16;c++){
    ushort4* ptr = (ushort4*)&U[(size_t)(bh*16 + c)*16384 + p];
    ushort4 t = *ptr;
    ushort4 w;
    w.x=f2bu(r0); w.y=f2bu(r1); w.z=f2bu(r2); w.w=f2bu(r3);
    *ptr = w;
    r0 += bu2f(t.x); r1 += bu2f(t.y); r2 += bu2f(t.z); r3 += bu2f(t.w);
  }
  if (sl == 0 && threadIdx.x < 128){
    float r = 0.f;
    for (int c=0;c<16;c++){
      float* q = &Esum[(size_t)(bh*16 + c)*128 + threadIdx.x];
      float t = *q; *q = r; r += t;
    }
  }
}

// ---------------- pass 3 (MFMA): o = qn@Cprev + causal(qn@e^T)@V + SumSq --
// 2 LDS buffers (68 KB -> 2 blocks/CU). Ut read DIRECT from global (no
// reuse; L2-resident). bufA: Q->qn->P->Ostage ; bufB: e->Vt(rotated).
__global__ __launch_bounds__(512, 4) void attn_pass3(
    const unsigned short* __restrict__ Eb, const unsigned short* __restrict__ Qb,
    const unsigned short* __restrict__ Vb, const unsigned short* __restrict__ U,
    const float* __restrict__ Esum, unsigned short* __restrict__ Oatt,
    float* __restrict__ SumSq)
{
  __shared__ unsigned short smem[2*128*LDSP];     // 68 KB
  __shared__ float seg_part[4*128];
  unsigned short* bufA = smem;
  unsigned short* bufB = smem + 128*LDSP;

  int tid = threadIdx.x;
  const int lane = tid & 63, quad = lane >> 4;
  const int w = tid >> 6, wm = w & 3, wn = w >> 2;
  const int Rb = wm*32, Cb = wn*64;
  int bh = blockIdx.x >> 4, ch = blockIdx.x & 15;
  int b = bh >> 3, h = bh & 7;
  size_t rowbase = (size_t)(b*T_SEQ + ch*128)*HIDN + h*128;
  const unsigned short* Ublk = U + (size_t)blockIdx.x*16384;

  // ---- stage Q, e ----
#pragma unroll
  for (int i=0;i<4;i++){
    int u = tid + i*512; int t = u >> 4, kc = (u & 15)*8;
    *(uint4*)&bufA[t*LDSP + kc] = *(const uint4*)&Qb[rowbase + (size_t)t*HIDN + kc];
    *(uint4*)&bufB[t*LDSP + kc] = *(const uint4*)&Eb[rowbase + (size_t)t*HIDN + kc];
  }
  __syncthreads();

  // ---- qn = q*SCALE/E_t ; 4-way segmented inclusive cumsum over t ----
  {
    int col = tid & 127, seg = tid >> 7;
    float psum = 0.f;
    for (int s = seg*32; s < seg*32+32; ++s) psum += bu2f(bufB[s*LDSP + col]);
    seg_part[seg*128 + col] = psum;
    __syncthreads();
    float run = Esum[(size_t)blockIdx.x*128 + col];
    for (int ss=0; ss<4; ++ss) if (ss < seg) run += seg_part[ss*128 + col];
    for (int s = seg*32; s < seg*32+32; ++s){
      run += bu2f(bufB[s*LDSP + col]);
      float q = bu2f(bufA[s*LDSP + col]);
      bufA[s*LDSP + col] = f2bu(q * SCALE * __builtin_amdgcn_rcpf(run));
    }
  }
  __syncthreads();

  // ---- inter: O = QN @ Ut^T (Ut direct from global) ; scores: P = QN@E^T --
  f32x4 accO[2][4] = {}, accP[2][4] = {};
  short8 av[2], bv[4];
#pragma unroll
  for (int k0=0; k0<128; k0+=32){
#pragma unroll
    for (int i=0;i<2;i++)
      av[i] = *(const short8*)(bufA + (Rb + i*16 + (lane&15))*LDSP + k0 + quad*8);
#pragma unroll
    for (int j=0;j<4;j++)
      bv[j] = *(const short8*)(Ublk + (size_t)(Cb + j*16 + (lane&15))*128 + k0 + quad*8);
#pragma unroll
    for (int i=0;i<2;i++)
#pragma unroll
      for (int j=0;j<4;j++)
        accO[i][j] = __builtin_amdgcn_mfma_f32_16x16x32_bf16(av[i], bv[j], accO[i][j], 0,0,0);
#pragma unroll
    for (int j=0;j<4;j++)
      bv[j] = *(const short8*)(bufB + (Cb + j*16 + (lane&15))*LDSP + k0 + quad*8);
#pragma unroll
    for (int i=0;i<2;i++)
#pragma unroll
      for (int j=0;j<4;j++)
        accP[i][j] = __builtin_amdgcn_mfma_f32_16x16x32_bf16(av[i], bv[j], accP[i][j], 0,0,0);
  }
  __syncthreads();

  // ---- masked P -> bufA [t][s] ; V^T -> bufB [v][s] (rotated store) ----
#pragma unroll
  for (int i=0;i<2;i++){
#pragma unroll
    for (int j=0;j<4;j++){
      int s = Cb + j*16 + (lane&15);
#pragma unroll
      for (int r=0;r<4;r++){
        int t = Rb + i*16 + quad*4 + r;
        bufA[t*LDSP + s] = f2bu(s <= t ? accP[i][j][r] : 0.f);
      }
    }
  }
#pragma unroll
  for (int i=0;i<4;i++){
    int u = tid + i*512; int t = u >> 4, kc = (u & 15)*8;
    int trot = (t + kc) & 127;
    unsigned short tmp[8];
    *(uint4*)tmp = *(const uint4*)&Vb[rowbase + (size_t)t*HIDN + kc];
#pragma unroll
    for (int j=0;j<8;j++) bufB[(kc+j)*LDSP + trot] = tmp[j];
  }
  __syncthreads();

  // ---- intra: O += P @ Vt^T (rotated bv reads) ----
#pragma unroll
  for (int k0=0; k0<128; k0+=32){
#pragma unroll
    for (int i=0;i<2;i++)
      av[i] = *(const short8*)(bufA + (Rb + i*16 + (lane&15))*LDSP + k0 + quad*8);
#pragma unroll
    for (int j=0;j<4;j++){
      int rb = Cb + j*16 + (lane&15);
      bv[j] = *(const short8*)(bufB + rb*LDSP + ((k0 + quad*8 + (rb & 120)) & 127));
    }
#pragma unroll
    for (int i=0;i<2;i++)
#pragma unroll
      for (int j=0;j<4;j++)
        accO[i][j] = __builtin_amdgcn_mfma_f32_16x16x32_bf16(av[i], bv[j], accO[i][j], 0,0,0);
  }
  __syncthreads();                        // all bufA (P) reads done

  // ---- O -> bufA (bf16) ----
#pragma unroll
  for (int i=0;i<2;i++){
#pragma unroll
    for (int j=0;j<4;j++){
      int v = Cb + j*16 + (lane&15);
#pragma unroll
      for (int r=0;r<4;r++){
        int t = Rb + i*16 + quad*4 + r;
        bufA[t*LDSP + v] = f2bu(accO[i][j][r]);
      }
    }
  }
  __syncthreads();

  // ---- per-row sum of squares (this head's 128 cols) ----
  {
    int seg = tid >> 7, row = tid & 127;
    float s = 0.f;
    for (int c = seg*32; c < seg*32+32; ++c){
      float x = bu2f(bufA[row*LDSP + c]); s += x*x;
    }
    seg_part[seg*128 + row] = s;
  }
  // ---- coalesced O write ----
#pragma unroll
  for (int i=0;i<4;i++){
    int u = tid + i*512; int t = u >> 4, kc = (u & 15)*8;
    *(uint4*)&Oatt[rowbase + (size_t)t*HIDN + kc] = *(const uint4*)&bufA[t*LDSP + kc];
  }
  __syncthreads();
  if (tid < 128){
    float s = seg_part[tid] + seg_part[128+tid] + seg_part[256+tid] + seg_part[384+tid];
    atomicAdd(&SumSq[(size_t)b*T_SEQ + ch*128 + tid], s);
  }
}

// ---- norm_gate2: elementwise RMSNorm(SumSq)*gnw*swish-gate -> bf16 -------
__global__ __launch_bounds__(256) void norm_gate2(
    const unsigned short* __restrict__ Oatt, const unsigned short* __restrict__ Gt,
    const unsigned short* __restrict__ gnw, const float* __restrict__ SumSq,
    unsigned short* __restrict__ Onorm)
{
  int row = blockIdx.x, tid = threadIdx.x;
  float rstd = rsqrtf(SumSq[row] * (1.f/1024.f) + 1e-5f);
  ushort4 o4 = *(const ushort4*)&Oatt[(size_t)row*HIDN + tid*4];
  ushort4 g4 = *(const ushort4*)&Gt  [(size_t)row*HIDN + tid*4];
  ushort4 w4 = *(const ushort4*)&gnw[tid*4];
  ushort4 r4;
  r4.x = f2bu(bu2f(o4.x) * rstd * bu2f(w4.x) * bu2f(g4.x));
  r4.y = f2bu(bu2f(o4.y) * rstd * bu2f(w4.y) * bu2f(g4.y));
  r4.z = f2bu(bu2f(o4.z) * rstd * bu2f(w4.z) * bu2f(g4.z));
  r4.w = f2bu(bu2f(o4.w) * rstd * bu2f(w4.w) * bu2f(g4.w));
  *(ushort4*)&Onorm[(size_t)row*HIDN + tid*4] = r4;
}

// ---------------- launch ----------------
extern "C" void kernel_launch(void* const* d_in, const int* in_sizes, int n_in,
                              void* d_out, int out_size, void* d_ws, size_t ws_size,
                              hipStream_t stream) {
  unsigned short* wsS = (unsigned short*)d_ws;     // ~69 MiB used

  unsigned short* Xc   = wsS;              // 4,194,304
  unsigned short* Wqc  = wsS + 4194304;
  unsigned short* Wkc  = wsS + 5242880;
  unsigned short* Wvc  = wsS + 6291456;
  unsigned short* Woc  = wsS + 7340032;
  unsigned short* Wg1c = wsS + 8388608;
  unsigned short* Wg2c = wsS + 8519680;
  unsigned short* gnwc = wsS + 8650752;
  unsigned short* Qb   = wsS + 8651776;
  unsigned short* Eb   = wsS + 12846080;   // e = exp(k), bf16
  unsigned short* Vb   = wsS + 17040384;
  unsigned short* G1b  = wsS + 21234688;
  unsigned short* Gt   = wsS + 21758976;
  unsigned short* Ub   = wsS + 25953280;
  unsigned short* Oattb= wsS + 30147584;
  float*          Esum = (float*)(wsS + 34341888);  // 32,768 floats
  float*          SumSq= (float*)(wsS + 34407424);  //  4,096 floats
  unsigned short* Onorm = Qb;              // Q dead after pass3

  convert_all<<<8453, 256, 0, stream>>>(
      (const float*)d_in[0], (const float*)d_in[1], (const float*)d_in[2],
      (const float*)d_in[3], (const float*)d_in[4], (const float*)d_in[5],
      (const float*)d_in[6], (const float*)d_in[7], wsS, SumSq);

  proj_kernel<<<dim3(32,25), 256, 0, stream>>>(Xc, Wqc, Wkc, Wvc, Wg1c, Qb, Eb, Vb, G1b);
  gemm_bt   <<<dim3(32,8),  256, 0, stream>>>(G1b, Wg2c, 128, HIDN, 1, nullptr, Gt);
  attn_pass1<<<256, 512, 0, stream>>>(Eb, Vb, Ub, Esum);
  attn_pass2<<<256, 256, 0, stream>>>(Ub, Esum);
  attn_pass3<<<256, 512, 0, stream>>>(Eb, Qb, Vb, Ub, Esum, Oattb, SumSq);
  norm_gate2<<<4096, 256, 0, stream>>>(Oattb, Gt, gnwc, SumSq, Onorm);
  gemm_bt   <<<dim3(32,8),  256, 0, stream>>>(Onorm, Woc, HIDN, HIDN, 0,
                                              (float*)d_out, nullptr);
}